// Round 1
// baseline (4451.402 us; speedup 1.0000x reference)
//
#include <hip/hip_runtime.h>
#include <math.h>

// NeuroSAT message passing, MI355X. Round 1: correct fp32 baseline.
// Key structural facts exploited:
//  - the 3-layer MLPs are purely affine -> collapsed to one 64x64 W + b (device-side, per launch)
//  - ch/cc only observable at clause nodes, lh/lc only at literal nodes
//  - lits->cls edges come grouped K=12 per clause; cls->lits needs CSR (built per launch)
//  - flip_perm is analytic: i<400 ? i+400 : i-400 within each problem block

#define H_     64
#define B_     16
#define NV2_   800      // 2*NV literals per problem
#define NC_    440
#define KK_    12
#define NPG_   1240     // nodes per problem
#define NLIT_  12800    // B*2NV
#define NCLS_  7040     // B*NC
#define NE_    84480    // B*NC*K
#define NN_    19840
#define STEPS_ 23       // ITERS-1

__device__ __forceinline__ float sigmf(float x) { return 1.0f / (1.0f + __expf(-x)); }
__device__ __forceinline__ float tanhf_(float x) { return 1.0f - 2.0f / (__expf(2.0f * x) + 1.0f); }

// ---------------- setup kernels ----------------

// Collapse the affine 3-layer MLPs. block 0: lm* -> Wl,bl; block 1: cm* -> Wc,bc; block 2: vote -> Wv,bv.
__global__ __launch_bounds__(256) void collapse_k(
    const float* lm1, const float* lm1b, const float* lm2, const float* lm2b, const float* lm3, const float* lm3b,
    const float* cm1, const float* cm1b, const float* cm2, const float* cm2b, const float* cm3, const float* cm3b,
    const float* lv1, const float* lv1b, const float* lv2, const float* lv2b, const float* lv3, const float* lv3b,
    float* Wl, float* bl, float* Wc, const float* /*unused*/, float* bc, float* Wv, float* bv)
{
    __shared__ float T[4096];
    __shared__ float ub[64];
    __shared__ float t3[64];
    int r = blockIdx.x, t = threadIdx.x;
    if (r < 2) {
        const float* w1 = r ? cm1 : lm1; const float* b1 = r ? cm1b : lm1b;
        const float* w2 = r ? cm2 : lm2; const float* b2 = r ? cm2b : lm2b;
        const float* w3 = r ? cm3 : lm3; const float* b3 = r ? cm3b : lm3b;
        float* W = r ? Wc : Wl;  float* bb = r ? bc : bl;
        for (int idx = t; idx < 4096; idx += 256) {
            int i = idx >> 6, j = idx & 63;
            float s = 0.f;
            for (int k = 0; k < 64; ++k) s += w1[i * 64 + k] * w2[k * 64 + j];
            T[idx] = s;
        }
        if (t < 64) {
            float s = 0.f;
            for (int k = 0; k < 64; ++k) s += b1[k] * w2[k * 64 + t];
            ub[t] = s + b2[t];
        }
        __syncthreads();
        for (int idx = t; idx < 4096; idx += 256) {
            int i = idx >> 6, j = idx & 63;
            float s = 0.f;
            for (int k = 0; k < 64; ++k) s += T[i * 64 + k] * w3[k * 64 + j];
            W[idx] = s;
        }
        if (t < 64) {
            float s = 0.f;
            for (int k = 0; k < 64; ++k) s += ub[k] * w3[k * 64 + t];
            bb[t] = s + b3[t];
        }
    } else {
        if (t < 64) {
            float s = 0.f;
            for (int j = 0; j < 64; ++j) s += lv2[t * 64 + j] * lv3[j];
            t3[t] = s;
            float s2 = 0.f;
            for (int k = 0; k < 64; ++k) s2 += lv1b[k] * lv2[k * 64 + t];
            ub[t] = s2 + lv2b[t];
        }
        __syncthreads();
        if (t < 64) {
            float s = 0.f;
            for (int k = 0; k < 64; ++k) s += lv1[t * 64 + k] * t3[k];
            Wv[t] = s;
        }
        if (t == 0) {
            float s = 0.f;
            for (int j = 0; j < 64; ++j) s += ub[j] * lv3[j];
            bv[0] = s + lv3b[0];
        }
    }
}

__global__ __launch_bounds__(256) void init_k(
    const float* x, const float* liw, const float* lib, const float* ciw, const float* cib,
    float* out0, float* outc, float* lh, float* lc, float* ch, float* cc)
{
    int t = blockIdx.x * 256 + threadIdx.x;
    if (t >= NN_ * 64) return;
    int node = t >> 6, j = t & 63;
    int b = node / NPG_;
    int i = node - b * NPG_;
    float x0 = x[node * 2 + 0], x1 = x[node * 2 + 1];
    if (i < NV2_) {
        int L = b * NV2_ + i;
        out0[L * 64 + j] = x0 * liw[j] + x1 * liw[64 + j] + lib[j];
        lh[L * 64 + j] = 0.f;
        lc[L * 64 + j] = 0.f;
    } else {
        int C = b * NC_ + (i - NV2_);
        outc[C * 64 + j] = x0 * ciw[j] + x1 * ciw[64 + j] + cib[j];
        ch[C * 64 + j] = 0.f;
        cc[C * 64 + j] = 0.f;
    }
}

// Convert edge src global node ids -> literal-local ids, count per-literal degree.
__global__ __launch_bounds__(256) void econv_k(const int* ei, int* llits, int* cnt)
{
    int e = blockIdx.x * 256 + threadIdx.x;
    if (e >= NE_) return;
    int g = ei[e];
    int b = g / NPG_;
    int i = g - b * NPG_;
    int L = b * NV2_ + i;
    llits[e] = L;
    atomicAdd(cnt + L, 1);
}

__global__ __launch_bounds__(1024) void scan_k(const int* cnt, int* rowptr, int* cursor)
{
    __shared__ int sums[1024];
    int t = threadIdx.x;
    int i0 = t * 13;
    int i1 = i0 + 13; if (i1 > NLIT_) i1 = NLIT_; if (i0 > NLIT_) i0 = NLIT_;
    int s = 0;
    for (int i = i0; i < i1; ++i) s += cnt[i];
    sums[t] = s;
    __syncthreads();
    for (int off = 1; off < 1024; off <<= 1) {
        int v = (t >= off) ? sums[t - off] : 0;
        __syncthreads();
        sums[t] += v;
        __syncthreads();
    }
    int run = sums[t] - s;  // exclusive prefix
    for (int i = i0; i < i1; ++i) { rowptr[i] = run; cursor[i] = run; run += cnt[i]; }
    if (t == 1023) rowptr[NLIT_] = sums[1023];
}

__global__ __launch_bounds__(256) void fill_k(const int* llits, int* cursor, int* col)
{
    int e = blockIdx.x * 256 + threadIdx.x;
    if (e >= NE_) return;
    int L = llits[e];
    int pos = atomicAdd(cursor + L, 1);
    col[pos] = e / KK_;     // clause local index
}

// ---------------- per-step kernels ----------------

// A: collapsed MLPs. tasks<800: literals (yl=MLPl, zl=MLPc); tasks>=800: clauses (ycls=MLPl(outc)).
// lane = row, weights via uniform (scalar) loads, acc in registers.
__global__ __launch_bounds__(64) void mlp_a_k(
    const float* cur, const float* outc,
    const float* Wl, const float* bl, const float* Wc, const float* bc,
    float* yl, float* zl, float* ycls)
{
    int task = blockIdx.x;
    int lane = threadIdx.x;
    const float *W, *bb, *src;
    float* dst;
    int grp, jb;
    if (task < 800) {
        grp = task >> 2;
        int c4 = task & 3;
        int m = c4 >> 1;
        jb = (c4 & 1) * 32;
        W = m ? Wc : Wl; bb = m ? bc : bl;
        src = cur; dst = m ? zl : yl;
    } else {
        int t2 = task - 800;
        grp = t2 >> 1;
        jb = (t2 & 1) * 32;
        W = Wl; bb = bl;
        src = outc; dst = ycls;
    }
    int row = grp * 64 + lane;
    const float4* u4 = (const float4*)(src + (size_t)row * 64);
    float acc[32];
#pragma unroll
    for (int j = 0; j < 32; ++j) acc[j] = bb[jb + j];
    for (int k4 = 0; k4 < 16; ++k4) {
        float4 uv = u4[k4];
        const float* wr0 = W + (k4 * 4 + 0) * 64 + jb;
        const float* wr1 = W + (k4 * 4 + 1) * 64 + jb;
        const float* wr2 = W + (k4 * 4 + 2) * 64 + jb;
        const float* wr3 = W + (k4 * 4 + 3) * 64 + jb;
#pragma unroll
        for (int j = 0; j < 32; ++j) {
            acc[j] += uv.x * wr0[j];
            acc[j] += uv.y * wr1[j];
            acc[j] += uv.z * wr2[j];
            acc[j] += uv.w * wr3[j];
        }
    }
    float* dp = dst + (size_t)row * 64 + jb;
#pragma unroll
    for (int j = 0; j < 32; ++j) dp[j] = acc[j];
}

// B: clause phase. gather l_msg -> clause LSTM cell -> zc = MLPc(ch_new). 64 clauses/block.
__global__ __launch_bounds__(256) void clause_k(
    const float* yl, const float* ycls, const int* llits,
    const float* wih, const float* whh, const float* bih, const float* bhh,
    const float* Wc, const float* bc,
    float* ch, float* cc, float* outc, float* zc)
{
    __shared__ float lmsg[64 * 65];
    __shared__ float hnew[64 * 65];
    int tid = threadIdx.x;
    int lane = tid & 63;
    int wv = __builtin_amdgcn_readfirstlane(tid >> 6);
    int blk = blockIdx.x;

    // gather: l_msg[c] = MLPl(out[c]) + sum_k MLPl(out)[lits[c,k]]   (self-loop = ycls)
    for (int s = wv * 16; s < wv * 16 + 16; ++s) {
        int c = blk * 64 + s;
        float a = ycls[(size_t)c * 64 + lane];
        const int* lp = llits + c * KK_;
#pragma unroll
        for (int k = 0; k < KK_; ++k) a += yl[(size_t)lp[k] * 64 + lane];
        lmsg[s * 65 + lane] = a;
    }
    __syncthreads();

    int c = blk * 64 + lane;   // lane = row
    int ucb = wv * 16;         // this wave's unit chunk
    float acc[64];
#pragma unroll
    for (int t = 0; t < 4; ++t)
#pragma unroll
        for (int q = 0; q < 16; ++q) acc[t * 16 + q] = bih[t * 64 + ucb + q] + bhh[t * 64 + ucb + q];

    // l_msg @ wih
#pragma unroll 4
    for (int k = 0; k < 64; ++k) {
        float uv = lmsg[lane * 65 + k];
        const float* wr = wih + k * 256 + ucb;
#pragma unroll
        for (int t = 0; t < 4; ++t)
#pragma unroll
            for (int q = 0; q < 16; ++q) acc[t * 16 + q] += uv * wr[t * 64 + q];
    }
    // ch @ whh
    {
        const float4* hp = (const float4*)(ch + (size_t)c * 64);
        for (int k4 = 0; k4 < 16; ++k4) {
            float4 uv = hp[k4];
            const float* wr0 = whh + (k4 * 4 + 0) * 256 + ucb;
            const float* wr1 = whh + (k4 * 4 + 1) * 256 + ucb;
            const float* wr2 = whh + (k4 * 4 + 2) * 256 + ucb;
            const float* wr3 = whh + (k4 * 4 + 3) * 256 + ucb;
#pragma unroll
            for (int t = 0; t < 4; ++t)
#pragma unroll
                for (int q = 0; q < 16; ++q) {
                    acc[t * 16 + q] += uv.x * wr0[t * 64 + q];
                    acc[t * 16 + q] += uv.y * wr1[t * 64 + q];
                    acc[t * 16 + q] += uv.z * wr2[t * 64 + q];
                    acc[t * 16 + q] += uv.w * wr3[t * 64 + q];
                }
        }
    }
    __syncthreads();   // all ch reads done before any ch writes

    // cell update: gates i,f,g,o for units [ucb, ucb+16) all live in this lane
#pragma unroll
    for (int q = 0; q < 16; ++q) {
        int u = ucb + q;
        float iv = sigmf(acc[q]);
        float fv = sigmf(acc[16 + q]);
        float gv = tanhf_(acc[32 + q]);
        float ov = sigmf(acc[48 + q]);
        float cp = cc[(size_t)c * 64 + u];
        float c2 = fv * cp + iv * gv;
        float h2 = ov * tanhf_(c2);
        cc[(size_t)c * 64 + u] = c2;
        ch[(size_t)c * 64 + u] = h2;
        outc[(size_t)c * 64 + u] = h2;
        hnew[lane * 65 + u] = h2;
    }
    __syncthreads();

    // zc = MLPc(ch_new); wave wv computes cols [ucb, ucb+16)
    float az[16];
#pragma unroll
    for (int j = 0; j < 16; ++j) az[j] = bc[ucb + j];
#pragma unroll 4
    for (int k = 0; k < 64; ++k) {
        float uv = hnew[lane * 65 + k];
        const float* wr = Wc + k * 64 + ucb;
#pragma unroll
        for (int j = 0; j < 16; ++j) az[j] += uv * wr[j];
    }
#pragma unroll
    for (int j = 0; j < 16; ++j) zc[(size_t)c * 64 + ucb + j] = az[j];
}

// C: literal phase. CSR gather c_msg -> literal LSTM (c_in = [out[flip] | c_msg]) -> lh, out_nxt.
__global__ __launch_bounds__(256) void lit_k(
    const float* cur, const float* zl, const float* zc,
    const int* rowptr, const int* col,
    const float* wih, const float* whh, const float* bih, const float* bhh,
    float* lh, float* lc, float* nxt)
{
    __shared__ float cmsg[64 * 65];
    int tid = threadIdx.x;
    int lane = tid & 63;
    int wv = __builtin_amdgcn_readfirstlane(tid >> 6);
    int blk = blockIdx.x;

    // gather: c_msg[l] = MLPc(out[l]) + sum_{c in csr[l]} MLPc(ch_new)[c]
    for (int s = wv * 16; s < wv * 16 + 16; ++s) {
        int l = blk * 64 + s;
        float a = zl[(size_t)l * 64 + lane];
        int r0 = rowptr[l], r1 = rowptr[l + 1];
        for (int idx = r0; idx < r1; ++idx) a += zc[(size_t)col[idx] * 64 + lane];
        cmsg[s * 65 + lane] = a;
    }
    __syncthreads();

    int l = blk * 64 + lane;   // lane = row
    int i = l % NV2_;
    int fi = (i < 400) ? i + 400 : i - 400;
    int fl = l - i + fi;
    int ucb = wv * 16;
    float acc[64];
#pragma unroll
    for (int t = 0; t < 4; ++t)
#pragma unroll
        for (int q = 0; q < 16; ++q) acc[t * 16 + q] = bih[t * 64 + ucb + q] + bhh[t * 64 + ucb + q];

    // part 1: out[flip] @ wih[0:64]
    {
        const float4* fp = (const float4*)(cur + (size_t)fl * 64);
        for (int k4 = 0; k4 < 16; ++k4) {
            float4 uv = fp[k4];
            const float* wr0 = wih + (k4 * 4 + 0) * 256 + ucb;
            const float* wr1 = wih + (k4 * 4 + 1) * 256 + ucb;
            const float* wr2 = wih + (k4 * 4 + 2) * 256 + ucb;
            const float* wr3 = wih + (k4 * 4 + 3) * 256 + ucb;
#pragma unroll
            for (int t = 0; t < 4; ++t)
#pragma unroll
                for (int q = 0; q < 16; ++q) {
                    acc[t * 16 + q] += uv.x * wr0[t * 64 + q];
                    acc[t * 16 + q] += uv.y * wr1[t * 64 + q];
                    acc[t * 16 + q] += uv.z * wr2[t * 64 + q];
                    acc[t * 16 + q] += uv.w * wr3[t * 64 + q];
                }
        }
    }
    // part 2: c_msg @ wih[64:128]
#pragma unroll 4
    for (int k = 0; k < 64; ++k) {
        float uv = cmsg[lane * 65 + k];
        const float* wr = wih + (64 + k) * 256 + ucb;
#pragma unroll
        for (int t = 0; t < 4; ++t)
#pragma unroll
            for (int q = 0; q < 16; ++q) acc[t * 16 + q] += uv * wr[t * 64 + q];
    }
    // part 3: lh @ whh
    {
        const float4* hp = (const float4*)(lh + (size_t)l * 64);
        for (int k4 = 0; k4 < 16; ++k4) {
            float4 uv = hp[k4];
            const float* wr0 = whh + (k4 * 4 + 0) * 256 + ucb;
            const float* wr1 = whh + (k4 * 4 + 1) * 256 + ucb;
            const float* wr2 = whh + (k4 * 4 + 2) * 256 + ucb;
            const float* wr3 = whh + (k4 * 4 + 3) * 256 + ucb;
#pragma unroll
            for (int t = 0; t < 4; ++t)
#pragma unroll
                for (int q = 0; q < 16; ++q) {
                    acc[t * 16 + q] += uv.x * wr0[t * 64 + q];
                    acc[t * 16 + q] += uv.y * wr1[t * 64 + q];
                    acc[t * 16 + q] += uv.z * wr2[t * 64 + q];
                    acc[t * 16 + q] += uv.w * wr3[t * 64 + q];
                }
        }
    }
    __syncthreads();   // all lh reads done before any lh writes

#pragma unroll
    for (int q = 0; q < 16; ++q) {
        int u = ucb + q;
        float iv = sigmf(acc[q]);
        float fv = sigmf(acc[16 + q]);
        float gv = tanhf_(acc[32 + q]);
        float ov = sigmf(acc[48 + q]);
        float cp = lc[(size_t)l * 64 + u];
        float c2 = fv * cp + iv * gv;
        float h2 = ov * tanhf_(c2);
        lc[(size_t)l * 64 + u] = c2;
        lh[(size_t)l * 64 + u] = h2;
        nxt[(size_t)l * 64 + u] = h2;
    }
}

__global__ __launch_bounds__(256) void vote_k(const float* outF, const float* Wv, const float* bv, float* out)
{
    int tid = threadIdx.x;
    int lane = tid & 63;
    int wv = tid >> 6;
    int node = blockIdx.x * 4 + wv;
    if (node >= NN_) return;
    int b = node / NPG_;
    int i = node - b * NPG_;
    float r = 0.f;
    if (i < NV2_) {
        int L = b * NV2_ + i;
        float v = outF[(size_t)L * 64 + lane] * Wv[lane];
#pragma unroll
        for (int off = 32; off > 0; off >>= 1) v += __shfl_down(v, off);
        r = v + bv[0];
    }
    if (lane == 0) out[node] = r;
}

// ---------------- host ----------------

extern "C" void kernel_launch(void* const* d_in, const int* in_sizes, int n_in,
                              void* d_out, int out_size, void* d_ws, size_t ws_size,
                              hipStream_t stream)
{
    const float* x    = (const float*)d_in[0];
    const int*   ei   = (const int*)d_in[2];      // edge_index row 0 (src), first NE_ entries are lits->cls
    const float* liw  = (const float*)d_in[4];
    const float* lib  = (const float*)d_in[5];
    const float* ciw  = (const float*)d_in[6];
    const float* cib  = (const float*)d_in[7];
    const float* lm1  = (const float*)d_in[8];
    const float* lm1b = (const float*)d_in[9];
    const float* lm2  = (const float*)d_in[10];
    const float* lm2b = (const float*)d_in[11];
    const float* lm3  = (const float*)d_in[12];
    const float* lm3b = (const float*)d_in[13];
    const float* cm1  = (const float*)d_in[14];
    const float* cm1b = (const float*)d_in[15];
    const float* cm2  = (const float*)d_in[16];
    const float* cm2b = (const float*)d_in[17];
    const float* cm3  = (const float*)d_in[18];
    const float* cm3b = (const float*)d_in[19];
    const float* lu_wih = (const float*)d_in[20];
    const float* lu_whh = (const float*)d_in[21];
    const float* lu_bih = (const float*)d_in[22];
    const float* lu_bhh = (const float*)d_in[23];
    const float* cu_wih = (const float*)d_in[24];
    const float* cu_whh = (const float*)d_in[25];
    const float* cu_bih = (const float*)d_in[26];
    const float* cu_bhh = (const float*)d_in[27];
    const float* lv1  = (const float*)d_in[28];
    const float* lv1b = (const float*)d_in[29];
    const float* lv2  = (const float*)d_in[30];
    const float* lv2b = (const float*)d_in[31];
    const float* lv3  = (const float*)d_in[32];
    const float* lv3b = (const float*)d_in[33];

    float* F = (float*)d_ws;
    size_t o = 0;
    auto A = [&](size_t n) { float* p = F + o; o += n; return p; };
    float* out0 = A((size_t)NLIT_ * 64);
    float* out1 = A((size_t)NLIT_ * 64);
    float* lh   = A((size_t)NLIT_ * 64);
    float* lc   = A((size_t)NLIT_ * 64);
    float* yl   = A((size_t)NLIT_ * 64);
    float* zl   = A((size_t)NLIT_ * 64);
    float* ycls = A((size_t)NCLS_ * 64);
    float* zc   = A((size_t)NCLS_ * 64);
    float* ch   = A((size_t)NCLS_ * 64);
    float* cc   = A((size_t)NCLS_ * 64);
    float* outc = A((size_t)NCLS_ * 64);
    float* Wl   = A(4096);
    float* Wc   = A(4096);
    float* bl   = A(64);
    float* bc   = A(64);
    float* Wv   = A(64);
    float* bv   = A(16);
    int* I = (int*)(F + o);
    int* llits  = I; I += NE_;
    int* rowptr = I; I += 12804;
    int* cursor = I; I += NLIT_;
    int* colA   = I; I += NE_;
    int* cnt    = I; I += NLIT_;

    hipMemsetAsync(cnt, 0, NLIT_ * sizeof(int), stream);
    collapse_k<<<3, 256, 0, stream>>>(lm1, lm1b, lm2, lm2b, lm3, lm3b,
                                      cm1, cm1b, cm2, cm2b, cm3, cm3b,
                                      lv1, lv1b, lv2, lv2b, lv3, lv3b,
                                      Wl, bl, Wc, nullptr, bc, Wv, bv);
    init_k<<<(NN_ * 64) / 256, 256, 0, stream>>>(x, liw, lib, ciw, cib, out0, outc, lh, lc, ch, cc);
    econv_k<<<NE_ / 256, 256, 0, stream>>>(ei, llits, cnt);
    scan_k<<<1, 1024, 0, stream>>>(cnt, rowptr, cursor);
    fill_k<<<NE_ / 256, 256, 0, stream>>>(llits, cursor, colA);

    float* bufs[2] = { out0, out1 };
    for (int s = 0; s < STEPS_; ++s) {
        const float* cur = bufs[s & 1];
        float* nx = bufs[(s + 1) & 1];
        mlp_a_k<<<1020, 64, 0, stream>>>(cur, outc, Wl, bl, Wc, bc, yl, zl, ycls);
        clause_k<<<NCLS_ / 64, 256, 0, stream>>>(yl, ycls, llits,
                                                 cu_wih, cu_whh, cu_bih, cu_bhh,
                                                 Wc, bc, ch, cc, outc, zc);
        lit_k<<<NLIT_ / 64, 256, 0, stream>>>(cur, zl, zc, rowptr, colA,
                                              lu_wih, lu_whh, lu_bih, lu_bhh,
                                              lh, lc, nx);
    }
    vote_k<<<NN_ / 4, 256, 0, stream>>>(bufs[STEPS_ & 1], Wv, bv, (float*)d_out);
}